// Round 5
// baseline (990.008 us; speedup 1.0000x reference)
//
#include <hip/hip_runtime.h>
#include <hip/hip_bf16.h>

#define DEV __device__ __forceinline__
typedef unsigned short u16;
using s16x8  = __attribute__((ext_vector_type(8))) short;
using f32x4v = __attribute__((ext_vector_type(4))) float;

constexpr float SCALE  = 0.0625f;   // 256^-0.5
constexpr float EPS    = 1e-8f;
constexpr float LN_EPS = 1e-5f;

DEV u16 f2bf(float f) {
    __hip_bfloat16 h = __float2bfloat16(f);
    u16 u; __builtin_memcpy(&u, &h, 2); return u;
}
DEV float bf2f(u16 u) {
    unsigned int x = ((unsigned int)u) << 16;
    float f; __builtin_memcpy(&f, &x, 4); return f;
}
DEV float ld1(const void* p, size_t i, int bf) {
    return bf ? bf2f(((const u16*)p)[i]) : ((const float*)p)[i];
}
DEV float warp_sum64(float v) {
    v += __shfl_xor(v, 1);  v += __shfl_xor(v, 2);  v += __shfl_xor(v, 4);
    v += __shfl_xor(v, 8);  v += __shfl_xor(v, 16); v += __shfl_xor(v, 32);
    return v;
}
DEV float sum16(float v) {
    v += __shfl_xor(v, 1); v += __shfl_xor(v, 2);
    v += __shfl_xor(v, 4); v += __shfl_xor(v, 8);
    return v;
}
DEV float sigf(float x) { return 1.f / (1.f + expf(-x)); }

// ---------------- dtype sniffer ----------------
__global__ void k_sniff(const void* __restrict__ x, int* __restrict__ flag) {
    int lane = threadIdx.x;
    u16 u = ((const u16*)x)[lane * 2];
    float v = bf2f(u);
    bool bad = !(fabsf(v) <= 1024.0f);
    unsigned long long m = __ballot(bad);
    if (lane == 0) *flag = (m == 0ull) ? 1 : 0;
}

// ---------------- small vectors -> canonical f32 ----------------
__global__ __launch_bounds__(256) void k_prep_misc(
    const void* bq, const void* bk, const void* bv, const void* bih, const void* bhh,
    const void* b1, const void* b2, const void* liw, const void* lib,
    const void* lsw, const void* lsb, const void* lfw, const void* lfb,
    float* o_bq, float* o_bk, float* o_bv, float* o_bih, float* o_bhh,
    float* o_b1, float* o_b2, float* o_liw, float* o_lib,
    float* o_lsw, float* o_lsb, float* o_lfw, float* o_lfb,
    const int* flagp) {
    int bf = *flagp;
    int i = blockIdx.x * 256 + threadIdx.x;
    if (i < 256) { o_bq[i]  = ld1(bq,  i, bf); return; } i -= 256;
    if (i < 256) { o_bk[i]  = ld1(bk,  i, bf); return; } i -= 256;
    if (i < 256) { o_bv[i]  = ld1(bv,  i, bf); return; } i -= 256;
    if (i < 768) { o_bih[i] = ld1(bih, i, bf); return; } i -= 768;
    if (i < 768) { o_bhh[i] = ld1(bhh, i, bf); return; } i -= 768;
    if (i < 512) { o_b1[i]  = ld1(b1,  i, bf); return; } i -= 512;
    if (i < 256) { o_b2[i]  = ld1(b2,  i, bf); return; } i -= 256;
    if (i < 256) { o_liw[i] = ld1(liw, i, bf); return; } i -= 256;
    if (i < 256) { o_lib[i] = ld1(lib, i, bf); return; } i -= 256;
    if (i < 256) { o_lsw[i] = ld1(lsw, i, bf); return; } i -= 256;
    if (i < 256) { o_lsb[i] = ld1(lsb, i, bf); return; } i -= 256;
    if (i < 256) { o_lfw[i] = ld1(lfw, i, bf); return; } i -= 256;
    if (i < 256) { o_lfb[i] = ld1(lfb, i, bf); }
}

// ---------------- weights -> bf16 (wqT, wvT transposed; wk2[n][d]=wk[d][n]*liw[n]) ----------------
__global__ __launch_bounds__(256) void k_prep_w(
    const void* wq, const void* wv, const void* wk,
    const void* wih, const void* whh, const void* w1, const void* w2,
    u16* wqT_b, u16* wvT_b, u16* wk2_b, u16* wih_b, u16* whh_b, u16* w1_b, u16* w2_b,
    const float* __restrict__ liw, const int* flagp) {
    int bf = *flagp;
    int i = blockIdx.x * 256 + threadIdx.x;
    if (i < 65536)  { int c=i>>8, d=i&255; wqT_b[i] = f2bf(ld1(wq, (size_t)d*256+c, bf)); return; } i -= 65536;
    if (i < 65536)  { int c=i>>8, d=i&255; wvT_b[i] = f2bf(ld1(wv, (size_t)d*256+c, bf)); return; } i -= 65536;
    if (i < 65536)  { int n=i>>8, d=i&255; wk2_b[i] = f2bf(ld1(wk, (size_t)d*256+n, bf) * liw[n]); return; } i -= 65536;
    if (i < 196608) { wih_b[i] = f2bf(ld1(wih, i, bf)); return; } i -= 196608;
    if (i < 196608) { whh_b[i] = f2bf(ld1(whh, i, bf)); return; } i -= 196608;
    if (i < 131072) { w1_b[i]  = f2bf(ld1(w1,  i, bf)); return; } i -= 131072;
    if (i < 131072) { w2_b[i]  = f2bf(ld1(w2,  i, bf)); }
}

// ---------------- m1[d]=sum_c wk[d][c]*lib[c] + bk[d]; m2[d]=-sum_c wk[d][c]*liw[c] ----------------
__global__ __launch_bounds__(256) void k_prep_m(const void* __restrict__ wk,
    const float* __restrict__ liw, const float* __restrict__ lib,
    const float* __restrict__ bk_f, float* __restrict__ m1p, float* __restrict__ m2p,
    const int* flagp) {
    int bf = *flagp;
    int wave = threadIdx.x >> 6, lane = threadIdx.x & 63;
    int d = blockIdx.x * 4 + wave;
    float s1 = 0.f, s2 = 0.f;
#pragma unroll
    for (int t = 0; t < 4; t++) {
        int c = lane * 4 + t;
        float w = ld1(wk, (size_t)d * 256 + c, bf);
        s1 += w * lib[c];
        s2 += w * liw[c];
    }
    s1 = warp_sum64(s1); s2 = warp_sum64(s2);
    if (lane == 0) { m1p[d] = s1 + bk_f[d]; m2p[d] = -s2; }
}

// ---------------- u1[c]=sum_d wq[d,c]m1[d]; u2; bq2[n]=liw[n]*sum_d bq[d]wk[d,n]; wibv[n]=sum_d wih[n,d]bv[d]; c12 ----------------
__global__ __launch_bounds__(256) void k_prep_u(
    const void* __restrict__ wq, const void* __restrict__ wk, const void* __restrict__ wih,
    const float* __restrict__ m1p, const float* __restrict__ m2p,
    const float* __restrict__ bq_f, const float* __restrict__ bv_f,
    const float* __restrict__ liw,
    float* __restrict__ u1, float* __restrict__ u2, float* __restrict__ bq2,
    float* __restrict__ wibv, float* __restrict__ c12, const int* flagp) {
    int bf = *flagp;
    int wave = threadIdx.x >> 6, lane = threadIdx.x & 63;
    int idx = blockIdx.x * 4 + wave;
    if (idx >= 1538) return;
    float s = 0.f;
#pragma unroll
    for (int t = 0; t < 4; t++) {
        int d = lane * 4 + t;
        if (idx < 256)       s += ld1(wq, (size_t)d*256 + idx, bf) * m1p[d];
        else if (idx < 512)  s += ld1(wq, (size_t)d*256 + (idx-256), bf) * m2p[d];
        else if (idx < 768)  s += bq_f[d] * ld1(wk, (size_t)d*256 + (idx-512), bf);
        else if (idx < 1536) s += ld1(wih, (size_t)(idx-768)*256 + d, bf) * bv_f[d];
        else if (idx == 1536) s += bq_f[d] * m1p[d];
        else                  s += bq_f[d] * m2p[d];
    }
    s = warp_sum64(s);
    if (lane == 0) {
        if (idx < 256)       u1[idx] = s;
        else if (idx < 512)  u2[idx-256] = s;
        else if (idx < 768)  bq2[idx-512] = s * liw[idx-512];
        else if (idx < 1536) wibv[idx-768] = s;
        else                 c12[idx-1536] = s;
    }
}

// ---------------- fused: LN stats + XT[b][c][j] bf16 (+ XB only if f32 input) ----------------
__global__ __launch_bounds__(256) void k_conv(const void* __restrict__ x,
    u16* __restrict__ XB, u16* __restrict__ XT,
    float* __restrict__ mu, float* __restrict__ rs, const int* flagp) {
    int bf = *flagp;
    int jt = blockIdx.x;      // 0..63: 64-row j tile
    int b  = blockIdx.y;      // 0..63
    int tid = threadIdx.x;
    __shared__ __attribute__((aligned(16))) u16 LT[64 * 264];   // [j][c], pad 8
    int jr   = tid >> 5;      // 0..7
    int cseg = tid & 31;      // 8-c segment
#pragma unroll
    for (int it = 0; it < 8; ++it) {
        int j = it * 8 + jr;
        size_t rowg = (size_t)b * 4096 + (size_t)jt * 64 + j;
        s16x8 val;
        float v[8];
        if (bf) {
            val = *(const s16x8*)((const u16*)x + rowg * 256 + cseg * 8);
#pragma unroll
            for (int e = 0; e < 8; e++) v[e] = bf2f((u16)val[e]);
        } else {
            const float4* sf = (const float4*)((const float*)x + rowg * 256 + cseg * 8);
            float4 f0 = sf[0], f1 = sf[1];
            v[0]=f0.x; v[1]=f0.y; v[2]=f0.z; v[3]=f0.w;
            v[4]=f1.x; v[5]=f1.y; v[6]=f1.z; v[7]=f1.w;
#pragma unroll
            for (int e = 0; e < 8; e++) val[e] = (short)f2bf(v[e]);
            *(s16x8*)(XB + rowg * 256 + cseg * 8) = val;   // materialize bf16 copy
        }
        *(s16x8*)(LT + j * 264 + cseg * 8) = val;
        float ps = 0.f, ps2 = 0.f;
#pragma unroll
        for (int e = 0; e < 8; e++) { ps += v[e]; ps2 += v[e] * v[e]; }
        ps  += __shfl_xor(ps, 1);  ps  += __shfl_xor(ps, 2);  ps  += __shfl_xor(ps, 4);
        ps  += __shfl_xor(ps, 8);  ps  += __shfl_xor(ps, 16);
        ps2 += __shfl_xor(ps2, 1); ps2 += __shfl_xor(ps2, 2); ps2 += __shfl_xor(ps2, 4);
        ps2 += __shfl_xor(ps2, 8); ps2 += __shfl_xor(ps2, 16);
        if (cseg == 0) {
            float m = ps * (1.f / 256.f);
            mu[rowg] = m;
            rs[rowg] = rsqrtf(ps2 * (1.f / 256.f) - m * m + LN_EPS);
        }
    }
    __syncthreads();
    // transpose read-out: thread = c, gather 64 j (scalar reads, 2 lanes/bank)
    int c = tid;
    u16* dst = XT + ((size_t)b * 256 + c) * 4096 + (size_t)jt * 64;
#pragma unroll
    for (int k = 0; k < 8; ++k) {
        s16x8 o;
#pragma unroll
        for (int t = 0; t < 8; t++) o[t] = (short)LT[(k * 8 + t) * 264 + c];
        *(s16x8*)(dst + k * 8) = o;
    }
}

// ---------------- slots init + LN(slots) + kap/lam ----------------
__global__ __launch_bounds__(256) void k_prep_s(const void* __restrict__ qp,
    const float* __restrict__ lsw, const float* __restrict__ lsb,
    const float* __restrict__ u1, const float* __restrict__ u2, const float* __restrict__ c12,
    float* __restrict__ slots, u16* __restrict__ Acat, u16* __restrict__ s_b,
    float* __restrict__ kap, float* __restrict__ lam, const int* flagp) {
    int bf = *flagp;
    int m = blockIdx.x;
    int s_ = m & 7, d = threadIdx.x;
    float v = ld1(qp, (size_t)s_ * 256 + d, bf);
    slots[(size_t)m*256 + d]   = v;
    Acat[(size_t)m*512 + 256 + d] = f2bf(v);
    __shared__ float red[16];
    float su = warp_sum64(v), sq = warp_sum64(v*v);
    int wave = threadIdx.x >> 6, lane = threadIdx.x & 63;
    if (lane == 0) { red[wave] = su; red[4+wave] = sq; }
    __syncthreads();
    float S1 = red[0]+red[1]+red[2]+red[3], S2 = red[4]+red[5]+red[6]+red[7];
    float muv = S1*(1.f/256.f);
    float rsv = rsqrtf(S2*(1.f/256.f) - muv*muv + LN_EPS);
    float sn = (v - muv)*rsv*lsw[d] + lsb[d];
    s_b[(size_t)m*256 + d] = f2bf(sn);
    float ks = warp_sum64(sn * u1[d]), ls = warp_sum64(sn * u2[d]);
    if (lane == 0) { red[8+wave] = ks; red[12+wave] = ls; }
    __syncthreads();
    if (threadIdx.x == 0) {
        kap[m] = red[8]+red[9]+red[10]+red[11] + c12[0];
        lam[m] = red[12]+red[13]+red[14]+red[15] + c12[1];
    }
}

// ---------------- 64x64 GEMM: C[M,N] = A[M,K].W[N,K]^T + bias ----------------
template<bool OUT_BF16, bool RELU>
__global__ __launch_bounds__(256) void gemm64(
    const u16* __restrict__ A, const u16* __restrict__ W,
    const float* __restrict__ bias, void* __restrict__ outp, int Nn, int K) {
    int m0 = blockIdx.x * 64, n0 = blockIdx.y * 64;
    int tid = threadIdx.x;
    int wave = tid >> 6, lane = tid & 63, quad = lane >> 4, l15 = lane & 15;
    int wm = wave >> 1, wn = wave & 1;
    __shared__ __attribute__((aligned(16))) u16 A_s[64*40];
    __shared__ __attribute__((aligned(16))) u16 B_s[64*40];
    f32x4v acc[2][2];
#pragma unroll
    for (int i = 0; i < 2; i++)
#pragma unroll
        for (int j = 0; j < 2; j++) acc[i][j] = (f32x4v){0.f,0.f,0.f,0.f};
    int r0 = tid >> 2, seg = tid & 3;
    int nkc = K >> 5;
    for (int kc = 0; kc < nkc; ++kc) {
        s16x8 a0 = *(const s16x8*)(A + (size_t)(m0 + r0)*K + kc*32 + seg*8);
        s16x8 b0 = *(const s16x8*)(W + (size_t)(n0 + r0)*K + kc*32 + seg*8);
        __syncthreads();
        *(s16x8*)(A_s + r0*40 + seg*8) = a0;
        *(s16x8*)(B_s + r0*40 + seg*8) = b0;
        __syncthreads();
        s16x8 af[2], bfr[2];
#pragma unroll
        for (int t = 0; t < 2; t++) af[t]  = *(const s16x8*)(A_s + (wm*32 + t*16 + l15)*40 + quad*8);
#pragma unroll
        for (int t = 0; t < 2; t++) bfr[t] = *(const s16x8*)(B_s + (wn*32 + t*16 + l15)*40 + quad*8);
#pragma unroll
        for (int ti = 0; ti < 2; ti++)
#pragma unroll
            for (int tj = 0; tj < 2; tj++)
                acc[ti][tj] = __builtin_amdgcn_mfma_f32_16x16x32_bf16(af[ti], bfr[tj], acc[ti][tj], 0, 0, 0);
    }
#pragma unroll
    for (int tj = 0; tj < 2; tj++) {
        int colg = n0 + wn*32 + tj*16 + l15;
        float bv_ = bias ? bias[colg] : 0.f;
#pragma unroll
        for (int ti = 0; ti < 2; ti++) {
            int rowb = m0 + wm*32 + ti*16 + quad*4;
#pragma unroll
            for (int r = 0; r < 4; r++) {
                float v = acc[ti][tj][r] + bv_;
                if (RELU) v = fmaxf(v, 0.f);
                if (OUT_BF16) ((u16*)outp)[(size_t)(rowb + r)*Nn + colg] = f2bf(v);
                else          ((float*)outp)[(size_t)(rowb + r)*Nn + colg] = v;
            }
        }
    }
}

// ---------------- assemble Wbig [1024][512] and bbig ----------------
__global__ __launch_bounds__(256) void k_big(const u16* __restrict__ Wc2_b,
    const u16* __restrict__ whh_b, const float* __restrict__ bih_f,
    const float* __restrict__ bhh_f, const float* __restrict__ wibv,
    u16* __restrict__ Wbig, float* __restrict__ bbig) {
    int idx = blockIdx.x * 256 + threadIdx.x;
    int n = idx >> 9, k = idx & 511;
    u16 v;
    if (n < 512)      v = (k < 256) ? Wc2_b[(size_t)n*256 + k] : whh_b[(size_t)n*256 + (k-256)];
    else if (n < 768) v = (k < 256) ? Wc2_b[(size_t)n*256 + k] : (u16)0;
    else              v = (k < 256) ? (u16)0 : whh_b[(size_t)(n-256)*256 + (k-256)];
    Wbig[idx] = v;
    if (idx < 1024) {
        float bb;
        if (idx < 512)      bb = bih_f[idx] + wibv[idx] + bhh_f[idx];
        else if (idx < 768) bb = bih_f[idx] + wibv[idx];
        else                bb = bhh_f[idx-256];
        bbig[idx] = bb;
    }
}

// ---------------- fused attention: dots + softmax + Z/R/T partials ----------------
__global__ __launch_bounds__(256) void k_attn(
    const void* __restrict__ xraw, const u16* __restrict__ XB,
    const u16* __restrict__ XT, const u16* __restrict__ q2b,
    const float* __restrict__ kap, const float* __restrict__ lam,
    const float* __restrict__ mu, const float* __restrict__ rs,
    const int* __restrict__ flagp,
    float* __restrict__ Zp, float* __restrict__ Rp, float* __restrict__ Tp) {
    int bf = *flagp;
    const u16* xb = bf ? (const u16*)xraw : XB;
    int jcc = blockIdx.x;   // 0..31, each covers 128 j (2 sub-tiles of 64)
    int b   = blockIdx.y;   // 0..63
    int tid = threadIdx.x;
    int wave = tid >> 6, lane = tid & 63, quad = lane >> 4, l15 = lane & 15;
    __shared__ __attribute__((aligned(16))) u16 q_s[16*264];
    __shared__ __attribute__((aligned(16))) u16 a_s[2][16*72];
    __shared__ float kl_s[32];
    {   // stage q2 rows 0..7, zero rows 8..15
        int row = tid >> 5, seg = tid & 31;
        s16x8 qv = *(const s16x8*)(q2b + (size_t)(b*8 + row)*256 + seg*8);
        *(s16x8*)(q_s + row*264 + seg*8) = qv;
        s16x8 z = {0,0,0,0,0,0,0,0};
        *(s16x8*)(q_s + (8+row)*264 + seg*8) = z;
    }
    if (tid < 16) {
        kl_s[tid]      = (tid < 8) ? kap[b*8 + tid] : 0.f;
        kl_s[16 + tid] = (tid < 8) ? lam[b*8 + tid] : 0.f;
    }
    __syncthreads();   // q_s, kl_s ready

    f32x4v accz[4];
#pragma unroll
    for (int t = 0; t < 4; t++) accz[t] = (f32x4v){0.f,0.f,0.f,0.f};
    float rtot[4] = {0.f,0.f,0.f,0.f}, ttot[4] = {0.f,0.f,0.f,0.f};
    int jb16 = wave * 16;
    const u16* xtb = XT + (size_t)b * 256 * 4096;

    for (int sub = 0; sub < 2; ++sub) {
        int jloc = (jcc*2 + sub) * 64;                    // j within batch
        size_t rowg = (size_t)b*4096 + jloc + jb16 + l15; // this lane's dots row
        // ---- dots: B-frags direct from global (16B/lane, line-coalesced) ----
        const u16* xbp = xb + rowg*256 + quad*8;
        s16x8 xv[8];
#pragma unroll
        for (int kc = 0; kc < 8; ++kc) xv[kc] = *(const s16x8*)(xbp + kc*32);
        f32x4v accd = (f32x4v){0.f,0.f,0.f,0.f};
#pragma unroll
        for (int kc = 0; kc < 8; ++kc) {
            s16x8 af = *(const s16x8*)(q_s + l15*264 + kc*32 + quad*8);
            accd = __builtin_amdgcn_mfma_f32_16x16x32_bf16(af, xv[kc], accd, 0, 0, 0);
        }
        // ---- issue Z-phase B-frag loads early (latency hides under softmax) ----
        s16x8 zv[8];
#pragma unroll
        for (int ct = 0; ct < 4; ++ct) {
            int c = wave*64 + ct*16 + l15;
#pragma unroll
            for (int kc2 = 0; kc2 < 2; ++kc2)
                zv[ct*2 + kc2] = *(const s16x8*)(xtb + (size_t)c*4096 + jloc + kc2*32 + quad*8);
        }
        // ---- affine fixup + softmax over i (pairs lane<->lane^16) ----
        float rsj = rs[rowg], mrj = mu[rowg] * rsj;
        float dv[4];
#pragma unroll
        for (int r = 0; r < 4; r++)
            dv[r] = SCALE*(rsj*accd[r] + mrj*kl_s[16 + quad*4 + r] + kl_s[quad*4 + r]);
        float mx = fmaxf(fmaxf(dv[0], dv[1]), fmaxf(dv[2], dv[3]));
        mx = fmaxf(mx, __shfl_xor(mx, 16));
        float ev[4];
        float sum = 0.f;
#pragma unroll
        for (int r = 0; r < 4; r++) { ev[r] = expf(dv[r] - mx); sum += ev[r]; }
        sum += __shfl_xor(sum, 16);
        float inv = 1.f / sum;
#pragma unroll
        for (int r = 0; r < 4; r++) {
            float a = ev[r]*inv + EPS;
            rtot[r] += a;
            ttot[r] += a * mrj;
            a_s[sub][(quad*4 + r)*72 + jb16 + l15] = f2bf(a * rsj);
        }
        __syncthreads();   // a_s[sub] ready (double-buffered: no pre-write barrier)
        // ---- Z += a2 . x (contract this sub's 64 j) ----
#pragma unroll
        for (int ct = 0; ct < 4; ++ct) {
#pragma unroll
            for (int kc2 = 0; kc2 < 2; ++kc2) {
                s16x8 af2 = *(const s16x8*)(a_s[sub] + l15*72 + kc2*32 + quad*8);
                accz[ct] = __builtin_amdgcn_mfma_f32_16x16x32_bf16(af2, zv[ct*2 + kc2], accz[ct], 0, 0, 0);
            }
        }
    }
    // ---- write partials ----
    if (quad < 2) {
#pragma unroll
        for (int ct = 0; ct < 4; ++ct) {
            int c = wave*64 + ct*16 + l15;
#pragma unroll
            for (int r = 0; r < 4; r++)
                Zp[((size_t)(b*32 + jcc)*8 + quad*4 + r)*256 + c] = accz[ct][r];
        }
    }
#pragma unroll
    for (int r = 0; r < 4; r++) {
        rtot[r] += __shfl_xor(rtot[r], 1);
        rtot[r] += __shfl_xor(rtot[r], 2);
        rtot[r] += __shfl_xor(rtot[r], 4);
        rtot[r] += __shfl_xor(rtot[r], 8);
        ttot[r] += __shfl_xor(ttot[r], 1);
        ttot[r] += __shfl_xor(ttot[r], 2);
        ttot[r] += __shfl_xor(ttot[r], 4);
        ttot[r] += __shfl_xor(ttot[r], 8);
    }
    if (l15 == 0 && quad < 2) {
        int base = ((b*32 + jcc)*4 + wave)*8 + quad*4;
#pragma unroll
        for (int r = 0; r < 4; r++) { Rp[base + r] = rtot[r]; Tp[base + r] = ttot[r]; }
    }
}

// ---------------- reduce Z/R/T -> Ys into A_cat cols 0..255 ----------------
__global__ __launch_bounds__(256) void k_reduce(const float* __restrict__ Zp,
    const float* __restrict__ Rp, const float* __restrict__ Tp,
    const float* __restrict__ liw, const float* __restrict__ lib,
    u16* __restrict__ Acat) {
    int m = blockIdx.x;   // b*8 + i
    int b = m >> 3, i = m & 7, d = threadIdx.x;
    float z = 0.f;
#pragma unroll
    for (int c = 0; c < 32; c++) z += Zp[((size_t)(b*32 + c)*8 + i)*256 + d];
    float rv = 0.f, tv = 0.f;
    if (d < 128) {
        rv = Rp[(size_t)(b*128 + d)*8 + i];
        tv = Tp[(size_t)(b*128 + d)*8 + i];
    }
    __shared__ float redR[4], redT[4];
    rv = warp_sum64(rv); tv = warp_sum64(tv);
    int wave = d >> 6, lane = d & 63;
    if (lane == 0) { redR[wave] = rv; redT[wave] = tv; }
    __syncthreads();
    float R = redR[0]+redR[1]+redR[2]+redR[3];
    float T = redT[0]+redT[1]+redT[2]+redT[3];
    float ys = (liw[d]*(z - T) + lib[d]*R) / R;
    Acat[(size_t)m*512 + d] = f2bf(ys);
}

// ---------------- fused slot-side chain: gates GEMM + GRU + LN_ff + FFN + residual
//                  + LN_s + kap/lam + q2 GEMM.  One block per 16 slot-rows. ----------------
__global__ __launch_bounds__(256) void k_slots(
    u16* __restrict__ Acat, float* __restrict__ slots,
    const u16* __restrict__ Wbig, const float* __restrict__ bbig,
    const u16* __restrict__ w1b, const float* __restrict__ b1f,
    const u16* __restrict__ w2b, const float* __restrict__ b2f,
    const u16* __restrict__ Wcb, const float* __restrict__ bq2,
    const float* __restrict__ lfw, const float* __restrict__ lfb,
    const float* __restrict__ lsw, const float* __restrict__ lsb,
    const float* __restrict__ u1, const float* __restrict__ u2,
    const float* __restrict__ c12,
    float* __restrict__ kap, float* __restrict__ lam,
    u16* __restrict__ q2b) {
    int m0 = blockIdx.x * 16;
    int tid = threadIdx.x;
    int w = tid >> 6, lane = tid & 63, quad = lane >> 4, l15 = lane & 15;
    __shared__ __attribute__((aligned(16))) u16 A_s[16*520];
    __shared__ __attribute__((aligned(16))) u16 hln_s[16*264];
    __shared__ __attribute__((aligned(16))) u16 ff1_s[16*520];
    __shared__ __attribute__((aligned(16))) u16 sn_s[16*264];
    __shared__ float red_a[4][16], red_b[4][16];

    // ---- stage Acat rows [16][512] -> LDS ----
#pragma unroll
    for (int it = 0; it < 4; ++it) {
        int chunk = it*256 + tid;
        int row = chunk >> 6, seg = chunk & 63;
        *(s16x8*)(A_s + row*520 + seg*8) =
            *(const s16x8*)(Acat + (size_t)(m0 + row)*512 + seg*8);
    }
    __syncthreads();

    // ---- P1+P2: gates GEMM (wave w owns d-slice w*64..w*64+63, all 4 gates) + GRU ----
    float h_reg[4][4];
    float su[4] = {0,0,0,0}, sq[4] = {0,0,0,0};
#pragma unroll
    for (int t = 0; t < 4; ++t) {
        int nbase = w*64 + t*16 + l15;
        int nr = nbase, nz = 256 + nbase, nn_ = 512 + nbase, nh = 768 + nbase;
        f32x4v ar = (f32x4v){0,0,0,0}, az = (f32x4v){0,0,0,0};
        f32x4v an = (f32x4v){0,0,0,0}, ah = (f32x4v){0,0,0,0};
#pragma unroll
        for (int kc = 0; kc < 16; ++kc) {
            s16x8 af = *(const s16x8*)(A_s + l15*520 + kc*32 + quad*8);
            s16x8 br = *(const s16x8*)(Wbig + (size_t)nr*512 + kc*32 + quad*8);
            s16x8 bz = *(const s16x8*)(Wbig + (size_t)nz*512 + kc*32 + quad*8);
            s16x8 bn = *(const s16x8*)(Wbig + (size_t)nn_*512 + kc*32 + quad*8);
            s16x8 bh = *(const s16x8*)(Wbig + (size_t)nh*512 + kc*32 + quad*8);
            ar = __builtin_amdgcn_mfma_f32_16x16x32_bf16(af, br, ar, 0, 0, 0);
            az = __builtin_amdgcn_mfma_f32_16x16x32_bf16(af, bz, az, 0, 0, 0);
            an = __builtin_amdgcn_mfma_f32_16x16x32_bf16(af, bn, an, 0, 0, 0);
            ah = __builtin_amdgcn_mfma_f32_16x16x32_bf16(af, bh, ah, 0, 0, 0);
        }
        float br_ = bbig[nr], bz_ = bbig[nz], bn_ = bbig[nn_], bh_ = bbig[nh];
        int d = w*64 + t*16 + l15;
#pragma unroll
        for (int r = 0; r < 4; ++r) {
            int m = quad*4 + r;
            float g_r = sigf(ar[r] + br_);
            float g_z = sigf(az[r] + bz_);
            float g_n = tanhf(an[r] + bn_ + g_r * (ah[r] + bh_));
            float sold = slots[(size_t)(m0 + m)*256 + d];
            float hv = (1.f - g_z)*g_n + g_z*sold;
            h_reg[t][r] = hv;
            su[r] += hv; sq[r] += hv*hv;
        }
    }
    // ---- LN_ff stats (cross-lane over l15, cross-wave via LDS) ----
#pragma unroll
    for (int r = 0; r < 4; ++r) { su[r] = sum16(su[r]); sq[r] = sum16(sq[r]); }
    if (l15 == 0) {
#pragma unroll
        for (int r = 0; r < 4; ++r) { red_a[w][quad*4 + r] = su[r]; red_b[w][quad*4 + r] = sq[r]; }
    }
    __syncthreads();
    float muv[4], rsv[4];
#pragma unroll
    for (int r = 0; r < 4; ++r) {
        int m = quad*4 + r;
        float S1 = red_a[0][m] + red_a[1][m] + red_a[2][m] + red_a[3][m];
        float S2 = red_b[0][m] + red_b[1][m] + red_b[2][m] + red_b[3][m];
        muv[r] = S1 * (1.f/256.f);
        rsv[r] = rsqrtf(S2 * (1.f/256.f) - muv[r]*muv[r] + LN_EPS);
    }
#pragma unroll
    for (int t = 0; t < 4; ++t) {
        int d = w*64 + t*16 + l15;
        float lw = lfw[d], lb = lfb[d];
#pragma unroll
        for (int r = 0; r < 4; ++r) {
            int m = quad*4 + r;
            hln_s[m*264 + d] = f2bf((h_reg[t][r] - muv[r])*rsv[r]*lw + lb);
        }
    }
    __syncthreads();

    // ---- P3: ff1 = relu(hln . w1^T + b1), [16 x 512] ----
#pragma unroll
    for (int nt = 0; nt < 8; ++nt) {
        int n = w*128 + nt*16 + l15;
        f32x4v acc = (f32x4v){0,0,0,0};
#pragma unroll
        for (int kc = 0; kc < 8; ++kc) {
            s16x8 af = *(const s16x8*)(hln_s + l15*264 + kc*32 + quad*8);
            s16x8 bf = *(const s16x8*)(w1b + (size_t)n*256 + kc*32 + quad*8);
            acc = __builtin_amdgcn_mfma_f32_16x16x32_bf16(af, bf, acc, 0, 0, 0);
        }
        float bv = b1f[n];
#pragma unroll
        for (int r = 0; r < 4; ++r)
            ff1_s[(quad*4 + r)*520 + n] = f2bf(fmaxf(acc[r] + bv, 0.f));
    }
    __syncthreads();

    // ---- P4: ff2 + residual -> slots_new; P5 stats pass 1 ----
    float sv_reg[4][4];
#pragma unroll
    for (int r = 0; r < 4; ++r) { su[r] = 0.f; sq[r] = 0.f; }
#pragma unroll
    for (int nt = 0; nt < 4; ++nt) {
        int n = w*64 + nt*16 + l15;   // = output d
        f32x4v acc = (f32x4v){0,0,0,0};
#pragma unroll
        for (int kc = 0; kc < 16; ++kc) {
            s16x8 af = *(const s16x8*)(ff1_s + l15*520 + kc*32 + quad*8);
            s16x8 bf = *(const s16x8*)(w2b + (size_t)n*512 + kc*32 + quad*8);
            acc = __builtin_amdgcn_mfma_f32_16x16x32_bf16(af, bf, acc, 0, 0, 0);
        }
        float bv = b2f[n];
#pragma unroll
        for (int r = 0; r < 4; ++r) {
            int m = quad*4 + r;
            float sv = acc[r] + bv + h_reg[nt][r];
            sv_reg[nt][r] = sv;
            su[r] += sv; sq[r] += sv*sv;
            slots[(size_t)(m0 + m)*256 + n] = sv;
            Acat[(size_t)(m0 + m)*512 + 256 + n] = f2bf(sv);
        }
    }
#pragma unroll
    for (int r = 0; r < 4; ++r) { su[r] = sum16(su[r]); sq[r] = sum16(sq[r]); }
    if (l15 == 0) {
#pragma unroll
        for (int r = 0; r < 4; ++r) { red_a[w][quad*4 + r] = su[r]; red_b[w][quad*4 + r] = sq[r]; }
    }
    __syncthreads();
#pragma unroll
    for (int r = 0; r < 4; ++r) {
        int m = quad*4 + r;
        float S1 = red_a[0][m] + red_a[1][m] + red_a[2][m] + red_a[3][m];
        float S2 = red_b[0][m] + red_b[1][m] + red_b[2][m] + red_b[3][m];
        muv[r] = S1 * (1.f/256.f);
        rsv[r] = rsqrtf(S2 * (1.f/256.f) - muv[r]*muv[r] + LN_EPS);
    }
    __syncthreads();   // everyone done reading red before ks/ls overwrite
    // ---- P5: sn + kap/lam partials ----
    float ks[4] = {0,0,0,0}, ls[4] = {0,0,0,0};
#pragma unroll
    for (int nt = 0; nt < 4; ++nt) {
        int d = w*64 + nt*16 + l15;
        float lw = lsw[d], lb = lsb[d], uu1 = u1[d], uu2 = u2[d];
#pragma unroll
        for (int r = 0; r < 4; ++r) {
            int m = quad*4 + r;
            float sn = (sv_reg[nt][r] - muv[r])*rsv[r]*lw + lb;
            sn_s[m*264 + d] = f2bf(sn);
            ks[r] += sn * uu1;
            ls[r] += sn * uu2;
        }
    }
#pragma unroll
    for (int r = 0; r < 4; ++r) { ks[r] = sum16(ks[r]); ls[r] = sum16(ls[r]); }
    if (l15 == 0) {
#pragma unroll
        for (int r = 0; r < 4; ++r) { red_a[w][quad*4 + r] = ks[r]; red_b[w][quad*4 + r] = ls[r]; }
    }
    __syncthreads();   // sn_s + red ready
    if (tid < 16) {
        int m = tid;
        kap[m0 + m] = red_a[0][m] + red_a[1][m] + red_a[2][m] + red_a[3][m] + c12[0];
        lam[m0 + m] = red_b[0][m] + red_b[1][m] + red_b[2][m] + red_b[3][m] + c12[1];
    }
    // ---- P6: q2 = sn . Wc^T + bq2 ----
#pragma unroll
    for (int nt = 0; nt < 4; ++nt) {
        int n = w*64 + nt*16 + l15;
        f32x4v acc = (f32x4v){0,0,0,0};
#pragma unroll
        for (int kc = 0; kc < 8; ++kc) {
            s16x8 af = *(const s16x8*)(sn_s + l15*264 + kc*32 + quad*8);
            s16x8 bf = *(const s16x8*)(Wcb + (size_t)n*256 + kc*32 + quad*8);
            acc = __builtin_amdgcn_mfma_f32_16x16x32_bf16(af, bf, acc, 0, 0, 0);
        }
        float bv = bq2[n];
#pragma unroll
        for (int r = 0; r < 4; ++r)
            q2b[(size_t)(m0 + quad*4 + r)*256 + n] = f2bf(acc[r] + bv);
    }
}

// ---------------- final output ----------------
__global__ __launch_bounds__(256) void k_out(const float* __restrict__ slots,
                                             void* __restrict__ out, const int* flagp) {
    int bf = *flagp;
    int i = blockIdx.x * 256 + threadIdx.x;
    if (bf) ((u16*)out)[i] = f2bf(slots[i]);
    else    ((float*)out)[i] = slots[i];
}

extern "C" void kernel_launch(void* const* d_in, const int* in_sizes, int n_in,
                              void* d_out, int out_size, void* d_ws, size_t ws_size,
                              hipStream_t stream) {
    (void)in_sizes; (void)n_in; (void)out_size; (void)ws_size;
    const void* inputs    = d_in[0];
    const void* query_pos = d_in[1];
    const void* wq   = d_in[2];  const void* bq   = d_in[3];
    const void* wk   = d_in[4];  const void* bk   = d_in[5];
    const void* wv   = d_in[6];  const void* bv   = d_in[7];
    const void* w_ih = d_in[8];  const void* b_ih = d_in[9];
    const void* w_hh = d_in[10]; const void* b_hh = d_in[11];
    const void* w1   = d_in[12]; const void* b1   = d_in[13];
    const void* w2   = d_in[14]; const void* b2   = d_in[15];
    const void* ln_in_w = d_in[16]; const void* ln_in_b = d_in[17];
    const void* ln_s_w  = d_in[18]; const void* ln_s_b  = d_in[19];
    const void* ln_ff_w = d_in[20]; const void* ln_ff_b = d_in[21];

    char* w = (char*)d_ws;
    size_t off = 0;
    auto alloc = [&](size_t bytes) -> void* {
        void* p = w + off;
        off = (off + bytes + 255) & ~(size_t)255;
        return p;
    };
    u16*   XB     = (u16*)alloc(134217728);    // [64][4096][256] bf16 (f32-input path only)
    u16*   XT     = (u16*)alloc(134217728);    // [64][256][4096] bf16
    float* Zp     = (float*)alloc(16777216);   // [64*32][8][256] f32
    u16*   Wbig_b = (u16*)alloc(1048576);      // [1024][512]
    u16*   Wc2_b  = (u16*)alloc(393216);       // [768][256]
    u16*   Wc_b   = (u16*)alloc(131072);       // [256][256]
    u16*   wqT_b  = (u16*)alloc(131072);
    u16*   wvT_b  = (u16*)alloc(131072);
    u16*   wk2_b  = (u16*)alloc(131072);
    u16*   wih_b  = (u16*)alloc(393216);
    u16*   whh_b  = (u16*)alloc(393216);
    u16*   w1_b   = (u16*)alloc(262144);
    u16*   w2_b   = (u16*)alloc(262144);
    float* mu     = (float*)alloc(1048576);
    float* rs     = (float*)alloc(1048576);
    float* slots  = (float*)alloc(524288);
    u16*   s_b    = (u16*)alloc(262144);
    u16*   Acat   = (u16*)alloc(524288);       // [512][512]: [Ys | slots]
    u16*   q2_b   = (u16*)alloc(262144);
    float* Rp     = (float*)alloc(262144);
    float* Tp     = (float*)alloc(262144);
    float* bq_f   = (float*)alloc(1024);
    float* bk_f   = (float*)alloc(1024);
    float* bv_f   = (float*)alloc(1024);
    float* bih_f  = (float*)alloc(3072);
    float* bhh_f  = (float*)alloc(3072);
    float* b1_f   = (float*)alloc(2048);
    float* b2_f   = (float*)alloc(1024);
    float* liw_f  = (float*)alloc(1024);
    float* lib_f  = (float*)alloc(1024);
    float* lsw_f  = (float*)alloc(1024);
    float* lsb_f  = (float*)alloc(1024);
    float* lfw_f  = (float*)alloc(1024);
    float* lfb_f  = (float*)alloc(1024);
    float* m1p    = (float*)alloc(1024);
    float* m2p    = (float*)alloc(1024);
    float* u1     = (float*)alloc(1024);
    float* u2     = (float*)alloc(1024);
    float* bq2    = (float*)alloc(1024);
    float* wibv   = (float*)alloc(3072);
    float* bbig   = (float*)alloc(4096);
    float* c12    = (float*)alloc(256);
    float* kap    = (float*)alloc(2048);
    float* lam    = (float*)alloc(2048);
    int*   flag   = (int*)alloc(256);

    // ---- prep ----
    k_sniff<<<1, 64, 0, stream>>>(inputs, flag);
    k_prep_misc<<<18, 256, 0, stream>>>(bq, bk, bv, b_ih, b_hh, b1, b2,
                                        ln_in_w, ln_in_b, ln_s_w, ln_s_b, ln_ff_w, ln_ff_b,
                                        bq_f, bk_f, bv_f, bih_f, bhh_f, b1_f, b2_f,
                                        liw_f, lib_f, lsw_f, lsb_f, lfw_f, lfb_f, flag);
    k_conv<<<dim3(64, 64), 256, 0, stream>>>(inputs, XB, XT, mu, rs, flag);
    k_prep_w<<<3328, 256, 0, stream>>>(wq, wv, wk, w_ih, w_hh, w1, w2,
                                       wqT_b, wvT_b, wk2_b, wih_b, whh_b, w1_b, w2_b,
                                       liw_f, flag);
    k_prep_m<<<64, 256, 0, stream>>>(wk, liw_f, lib_f, bk_f, m1p, m2p, flag);
    k_prep_u<<<385, 256, 0, stream>>>(wq, wk, w_ih, m1p, m2p, bq_f, bv_f, liw_f,
                                      u1, u2, bq2, wibv, c12, flag);
    k_prep_s<<<512, 256, 0, stream>>>(query_pos, lsw_f, lsb_f, u1, u2, c12,
                                      slots, Acat, s_b, kap, lam, flag);
    gemm64<true, false><<<dim3(4, 4), 256, 0, stream>>>(wk2_b, wqT_b, nullptr, Wc_b, 256, 256);
    gemm64<true, false><<<dim3(12, 4), 256, 0, stream>>>(wih_b, wvT_b, nullptr, Wc2_b, 256, 256);
    k_big<<<2048, 256, 0, stream>>>(Wc2_b, whh_b, bih_f, bhh_f, wibv, Wbig_b, bbig);
    gemm64<true, false><<<dim3(8, 4), 256, 0, stream>>>(s_b, Wc_b, bq2, q2_b, 256, 256);

    // ---- iterations: 3 kernels per step ----
    for (int step = 0; step < 4; ++step) {
        k_attn<<<dim3(32, 64), 256, 0, stream>>>(inputs, XB, XT, q2_b, kap, lam, mu, rs, flag, Zp, Rp, Tp);
        k_reduce<<<512, 256, 0, stream>>>(Zp, Rp, Tp, liw_f, lib_f, Acat);
        k_slots<<<32, 256, 0, stream>>>(Acat, slots, Wbig_b, bbig, w1_b, b1_f,
                                        w2_b, b2_f, Wc_b, bq2, lfw_f, lfb_f,
                                        lsw_f, lsb_f, u1, u2, c12, kap, lam, q2_b);
    }
    k_out<<<512, 256, 0, stream>>>(slots, d_out, flag);
}

// Round 7
// 726.074 us; speedup vs baseline: 1.3635x; 1.3635x over previous
//
#include <hip/hip_runtime.h>
#include <hip/hip_bf16.h>

#define DEV __device__ __forceinline__
typedef unsigned short u16;
using s16x8  = __attribute__((ext_vector_type(8))) short;
using f32x4v = __attribute__((ext_vector_type(4))) float;

constexpr float SCALE  = 0.0625f;   // 256^-0.5
constexpr float EPS    = 1e-8f;
constexpr float LN_EPS = 1e-5f;

DEV u16 f2bf(float f) {
    __hip_bfloat16 h = __float2bfloat16(f);
    u16 u; __builtin_memcpy(&u, &h, 2); return u;
}
DEV float bf2f(u16 u) {
    unsigned int x = ((unsigned int)u) << 16;
    float f; __builtin_memcpy(&f, &x, 4); return f;
}
DEV float ld1(const void* p, size_t i, int bf) {
    return bf ? bf2f(((const u16*)p)[i]) : ((const float*)p)[i];
}
DEV float warp_sum64(float v) {
    v += __shfl_xor(v, 1);  v += __shfl_xor(v, 2);  v += __shfl_xor(v, 4);
    v += __shfl_xor(v, 8);  v += __shfl_xor(v, 16); v += __shfl_xor(v, 32);
    return v;
}
DEV float sigf(float x) { return 1.f / (1.f + expf(-x)); }

// T_s swizzled address: banks of the Z-gather spread over all 32 (see round notes)
DEV int ts_addr(int cb, int j) { return cb*632 + j*8 + ((j>>3)<<4); }

// ---------------- dtype sniffer ----------------
__global__ void k_sniff(const void* __restrict__ x, int* __restrict__ flag) {
    int lane = threadIdx.x;
    u16 u = ((const u16*)x)[lane * 2];
    float v = bf2f(u);
    bool bad = !(fabsf(v) <= 1024.0f);
    unsigned long long m = __ballot(bad);
    if (lane == 0) *flag = (m == 0ull) ? 1 : 0;
}

// ---------------- small vectors -> canonical f32 ----------------
__global__ __launch_bounds__(256) void k_prep_misc(
    const void* bq, const void* bk, const void* bv, const void* bih, const void* bhh,
    const void* b1, const void* b2, const void* liw, const void* lib,
    const void* lsw, const void* lsb, const void* lfw, const void* lfb,
    float* o_bq, float* o_bk, float* o_bv, float* o_bih, float* o_bhh,
    float* o_b1, float* o_b2, float* o_liw, float* o_lib,
    float* o_lsw, float* o_lsb, float* o_lfw, float* o_lfb,
    const int* flagp) {
    int bf = *flagp;
    int i = blockIdx.x * 256 + threadIdx.x;
    if (i < 256) { o_bq[i]  = ld1(bq,  i, bf); return; } i -= 256;
    if (i < 256) { o_bk[i]  = ld1(bk,  i, bf); return; } i -= 256;
    if (i < 256) { o_bv[i]  = ld1(bv,  i, bf); return; } i -= 256;
    if (i < 768) { o_bih[i] = ld1(bih, i, bf); return; } i -= 768;
    if (i < 768) { o_bhh[i] = ld1(bhh, i, bf); return; } i -= 768;
    if (i < 512) { o_b1[i]  = ld1(b1,  i, bf); return; } i -= 512;
    if (i < 256) { o_b2[i]  = ld1(b2,  i, bf); return; } i -= 256;
    if (i < 256) { o_liw[i] = ld1(liw, i, bf); return; } i -= 256;
    if (i < 256) { o_lib[i] = ld1(lib, i, bf); return; } i -= 256;
    if (i < 256) { o_lsw[i] = ld1(lsw, i, bf); return; } i -= 256;
    if (i < 256) { o_lsb[i] = ld1(lsb, i, bf); return; } i -= 256;
    if (i < 256) { o_lfw[i] = ld1(lfw, i, bf); return; } i -= 256;
    if (i < 256) { o_lfb[i] = ld1(lfb, i, bf); }
}

// ---------------- weights -> bf16 (wqT, wvT transposed; wk2[n][d]=wk[d][n]*liw[n]) ----------------
__global__ __launch_bounds__(256) void k_prep_w(
    const void* wq, const void* wv, const void* wk,
    const void* wih, const void* whh, const void* w1, const void* w2,
    u16* wqT_b, u16* wvT_b, u16* wk2_b, u16* wih_b, u16* whh_b, u16* w1_b, u16* w2_b,
    const float* __restrict__ liw, const int* flagp) {
    int bf = *flagp;
    int i = blockIdx.x * 256 + threadIdx.x;
    if (i < 65536)  { int c=i>>8, d=i&255; wqT_b[i] = f2bf(ld1(wq, (size_t)d*256+c, bf)); return; } i -= 65536;
    if (i < 65536)  { int c=i>>8, d=i&255; wvT_b[i] = f2bf(ld1(wv, (size_t)d*256+c, bf)); return; } i -= 65536;
    if (i < 65536)  { int n=i>>8, d=i&255; wk2_b[i] = f2bf(ld1(wk, (size_t)d*256+n, bf) * liw[n]); return; } i -= 65536;
    if (i < 196608) { wih_b[i] = f2bf(ld1(wih, i, bf)); return; } i -= 196608;
    if (i < 196608) { whh_b[i] = f2bf(ld1(whh, i, bf)); return; } i -= 196608;
    if (i < 131072) { w1_b[i]  = f2bf(ld1(w1,  i, bf)); return; } i -= 131072;
    if (i < 131072) { w2_b[i]  = f2bf(ld1(w2,  i, bf)); }
}

// ---------------- m1[d]=sum_c wk[d][c]*lib[c] + bk[d]; m2[d]=-sum_c wk[d][c]*liw[c] ----------------
__global__ __launch_bounds__(256) void k_prep_m(const void* __restrict__ wk,
    const float* __restrict__ liw, const float* __restrict__ lib,
    const float* __restrict__ bk_f, float* __restrict__ m1p, float* __restrict__ m2p,
    const int* flagp) {
    int bf = *flagp;
    int wave = threadIdx.x >> 6, lane = threadIdx.x & 63;
    int d = blockIdx.x * 4 + wave;
    float s1 = 0.f, s2 = 0.f;
#pragma unroll
    for (int t = 0; t < 4; t++) {
        int c = lane * 4 + t;
        float w = ld1(wk, (size_t)d * 256 + c, bf);
        s1 += w * lib[c];
        s2 += w * liw[c];
    }
    s1 = warp_sum64(s1); s2 = warp_sum64(s2);
    if (lane == 0) { m1p[d] = s1 + bk_f[d]; m2p[d] = -s2; }
}

// ---------------- u1[c]=sum_d wq[d,c]m1[d]; u2; bq2[n]=liw[n]*sum_d bq[d]wk[d,n]; wibv[n]=sum_d wih[n,d]bv[d]; c12 ----------------
__global__ __launch_bounds__(256) void k_prep_u(
    const void* __restrict__ wq, const void* __restrict__ wk, const void* __restrict__ wih,
    const float* __restrict__ m1p, const float* __restrict__ m2p,
    const float* __restrict__ bq_f, const float* __restrict__ bv_f,
    const float* __restrict__ liw,
    float* __restrict__ u1, float* __restrict__ u2, float* __restrict__ bq2,
    float* __restrict__ wibv, float* __restrict__ c12, const int* flagp) {
    int bf = *flagp;
    int wave = threadIdx.x >> 6, lane = threadIdx.x & 63;
    int idx = blockIdx.x * 4 + wave;
    if (idx >= 1538) return;
    float s = 0.f;
#pragma unroll
    for (int t = 0; t < 4; t++) {
        int d = lane * 4 + t;
        if (idx < 256)       s += ld1(wq, (size_t)d*256 + idx, bf) * m1p[d];
        else if (idx < 512)  s += ld1(wq, (size_t)d*256 + (idx-256), bf) * m2p[d];
        else if (idx < 768)  s += bq_f[d] * ld1(wk, (size_t)d*256 + (idx-512), bf);
        else if (idx < 1536) s += ld1(wih, (size_t)(idx-768)*256 + d, bf) * bv_f[d];
        else if (idx == 1536) s += bq_f[d] * m1p[d];
        else                  s += bq_f[d] * m2p[d];
    }
    s = warp_sum64(s);
    if (lane == 0) {
        if (idx < 256)       u1[idx] = s;
        else if (idx < 512)  u2[idx-256] = s;
        else if (idx < 768)  bq2[idx-512] = s * liw[idx-512];
        else if (idx < 1536) wibv[idx-768] = s;
        else                 c12[idx-1536] = s;
    }
}

// ---------------- per-row LN stats of inputs (+ bf16 copy XB on f32 path) ----------------
__global__ __launch_bounds__(256) void k_stats(const void* __restrict__ x,
                                               u16* __restrict__ XB,
                                               float* __restrict__ mu,
                                               float* __restrict__ rs,
                                               const int* flagp) {
    int bf = *flagp;
    int wave = threadIdx.x >> 6, lane = threadIdx.x & 63;
    int row  = blockIdx.x * 4 + wave;
    float v[4];
    if (bf) {
        u16 a4[4];
        __builtin_memcpy(a4, (const u16*)x + (size_t)row * 256 + lane * 4, 8);
#pragma unroll
        for (int i = 0; i < 4; i++) v[i] = bf2f(a4[i]);
    } else {
        float4 f = *(const float4*)((const float*)x + (size_t)row * 256 + lane * 4);
        v[0]=f.x; v[1]=f.y; v[2]=f.z; v[3]=f.w;
        u16 b4[4];
#pragma unroll
        for (int i = 0; i < 4; i++) b4[i] = f2bf(v[i]);
        __builtin_memcpy(XB + (size_t)row * 256 + lane * 4, b4, 8);
    }
    float s  = v[0]+v[1]+v[2]+v[3];
    float s2 = v[0]*v[0]+v[1]*v[1]+v[2]*v[2]+v[3]*v[3];
    s = warp_sum64(s); s2 = warp_sum64(s2);
    if (lane == 0) {
        float m = s * (1.f/256.f);
        mu[row] = m;
        rs[row] = rsqrtf(s2 * (1.f/256.f) - m*m + LN_EPS);
    }
}

// ---------------- slots init + LN(slots) + kap/lam ----------------
__global__ __launch_bounds__(256) void k_prep_s(const void* __restrict__ qp,
    const float* __restrict__ lsw, const float* __restrict__ lsb,
    const float* __restrict__ u1, const float* __restrict__ u2, const float* __restrict__ c12,
    float* __restrict__ slots, u16* __restrict__ Acat, u16* __restrict__ s_b,
    float* __restrict__ kap, float* __restrict__ lam, const int* flagp) {
    int bf = *flagp;
    int m = blockIdx.x;
    int s_ = m & 7, d = threadIdx.x;
    float v = ld1(qp, (size_t)s_ * 256 + d, bf);
    slots[(size_t)m*256 + d]   = v;
    Acat[(size_t)m*512 + 256 + d] = f2bf(v);
    __shared__ float red[16];
    float su = warp_sum64(v), sq = warp_sum64(v*v);
    int wave = threadIdx.x >> 6, lane = threadIdx.x & 63;
    if (lane == 0) { red[wave] = su; red[4+wave] = sq; }
    __syncthreads();
    float S1 = red[0]+red[1]+red[2]+red[3], S2 = red[4]+red[5]+red[6]+red[7];
    float muv = S1*(1.f/256.f);
    float rsv = rsqrtf(S2*(1.f/256.f) - muv*muv + LN_EPS);
    float sn = (v - muv)*rsv*lsw[d] + lsb[d];
    s_b[(size_t)m*256 + d] = f2bf(sn);
    float ks = warp_sum64(sn * u1[d]), ls = warp_sum64(sn * u2[d]);
    if (lane == 0) { red[8+wave] = ks; red[12+wave] = ls; }
    __syncthreads();
    if (threadIdx.x == 0) {
        kap[m] = red[8]+red[9]+red[10]+red[11] + c12[0];
        lam[m] = red[12]+red[13]+red[14]+red[15] + c12[1];
    }
}

// ---------------- 64x64 GEMM: C[M,N] = A[M,K].W[N,K]^T + bias ----------------
template<bool OUT_BF16, bool RELU>
__global__ __launch_bounds__(256) void gemm64(
    const u16* __restrict__ A, const u16* __restrict__ W,
    const float* __restrict__ bias, void* __restrict__ outp, int Nn, int K) {
    int m0 = blockIdx.x * 64, n0 = blockIdx.y * 64;
    int tid = threadIdx.x;
    int wave = tid >> 6, lane = tid & 63, quad = lane >> 4, l15 = lane & 15;
    int wm = wave >> 1, wn = wave & 1;
    __shared__ __attribute__((aligned(16))) u16 A_s[64*40];
    __shared__ __attribute__((aligned(16))) u16 B_s[64*40];
    f32x4v acc[2][2];
#pragma unroll
    for (int i = 0; i < 2; i++)
#pragma unroll
        for (int j = 0; j < 2; j++) acc[i][j] = (f32x4v){0.f,0.f,0.f,0.f};
    int r0 = tid >> 2, seg = tid & 3;
    int nkc = K >> 5;
    for (int kc = 0; kc < nkc; ++kc) {
        s16x8 a0 = *(const s16x8*)(A + (size_t)(m0 + r0)*K + kc*32 + seg*8);
        s16x8 b0 = *(const s16x8*)(W + (size_t)(n0 + r0)*K + kc*32 + seg*8);
        __syncthreads();
        *(s16x8*)(A_s + r0*40 + seg*8) = a0;
        *(s16x8*)(B_s + r0*40 + seg*8) = b0;
        __syncthreads();
        s16x8 af[2], bfr[2];
#pragma unroll
        for (int t = 0; t < 2; t++) af[t]  = *(const s16x8*)(A_s + (wm*32 + t*16 + l15)*40 + quad*8);
#pragma unroll
        for (int t = 0; t < 2; t++) bfr[t] = *(const s16x8*)(B_s + (wn*32 + t*16 + l15)*40 + quad*8);
#pragma unroll
        for (int ti = 0; ti < 2; ti++)
#pragma unroll
            for (int tj = 0; tj < 2; tj++)
                acc[ti][tj] = __builtin_amdgcn_mfma_f32_16x16x32_bf16(af[ti], bfr[tj], acc[ti][tj], 0, 0, 0);
    }
#pragma unroll
    for (int tj = 0; tj < 2; tj++) {
        int colg = n0 + wn*32 + tj*16 + l15;
        float bv_ = bias ? bias[colg] : 0.f;
#pragma unroll
        for (int ti = 0; ti < 2; ti++) {
            int rowb = m0 + wm*32 + ti*16 + quad*4;
#pragma unroll
            for (int r = 0; r < 4; r++) {
                float v = acc[ti][tj][r] + bv_;
                if (RELU) v = fmaxf(v, 0.f);
                if (OUT_BF16) ((u16*)outp)[(size_t)(rowb + r)*Nn + colg] = f2bf(v);
                else          ((float*)outp)[(size_t)(rowb + r)*Nn + colg] = v;
            }
        }
    }
}

// ---------------- assemble Wbig [1024][512] and bbig ----------------
__global__ __launch_bounds__(256) void k_big(const u16* __restrict__ Wc2_b,
    const u16* __restrict__ whh_b, const float* __restrict__ bih_f,
    const float* __restrict__ bhh_f, const float* __restrict__ wibv,
    u16* __restrict__ Wbig, float* __restrict__ bbig) {
    int idx = blockIdx.x * 256 + threadIdx.x;
    int n = idx >> 9, k = idx & 511;
    u16 v;
    if (n < 512)      v = (k < 256) ? Wc2_b[(size_t)n*256 + k] : whh_b[(size_t)n*256 + (k-256)];
    else if (n < 768) v = (k < 256) ? Wc2_b[(size_t)n*256 + k] : (u16)0;
    else              v = (k < 256) ? (u16)0 : whh_b[(size_t)(n-256)*256 + (k-256)];
    Wbig[idx] = v;
    if (idx < 1024) {
        float bb;
        if (idx < 512)      bb = bih_f[idx] + wibv[idx] + bhh_f[idx];
        else if (idx < 768) bb = bih_f[idx] + wibv[idx];
        else                bb = bhh_f[idx-256];
        bbig[idx] = bb;
    }
}

// ---------------- fused attention: dots + softmax + Z/R/T partials ----------------
// Dots B-operand direct from global (row-major bf16 x). T_s staged (swizzled layout,
// conflict-free Z gather) only for the Z contraction.
__global__ __launch_bounds__(256) void k_attn(
    const void* __restrict__ xraw, const u16* __restrict__ XB,
    const u16* __restrict__ q2b,
    const float* __restrict__ kap, const float* __restrict__ lam,
    const float* __restrict__ mu, const float* __restrict__ rs,
    const int* __restrict__ flagp,
    float* __restrict__ Zp, float* __restrict__ Rp, float* __restrict__ Tp) {
    int bf = *flagp;
    const u16* xb = bf ? (const u16*)xraw : XB;
    int jcc = blockIdx.x;   // 0..31, each covers 128 j (2 sub-tiles of 64)
    int b   = blockIdx.y;   // 0..63
    int tid = threadIdx.x;
    int wave = tid >> 6, lane = tid & 63, quad = lane >> 4, l15 = lane & 15;
    __shared__ __attribute__((aligned(16))) u16 q_s[8*264];
    __shared__ __attribute__((aligned(16))) u16 a_s[16*72];
    __shared__ __attribute__((aligned(16))) u16 T_s[32*632];
    __shared__ float kl_s[32];
    {   // stage q2 rows 0..7
        int row = tid >> 5, seg = tid & 31;
        s16x8 qv = *(const s16x8*)(q2b + (size_t)(b*8 + row)*256 + seg*8);
        *(s16x8*)(q_s + row*264 + seg*8) = qv;
    }
    if (tid < 16) {
        kl_s[tid]      = (tid < 8) ? kap[b*8 + tid] : 0.f;
        kl_s[16 + tid] = (tid < 8) ? lam[b*8 + tid] : 0.f;
    }
    f32x4v accz[4];
#pragma unroll
    for (int t = 0; t < 4; t++) accz[t] = (f32x4v){0.f,0.f,0.f,0.f};
    float rtot[4] = {0.f,0.f,0.f,0.f}, ttot[4] = {0.f,0.f,0.f,0.f};
    int jb16 = wave * 16;
    int jrow = tid >> 5, cseg = tid & 31;   // staging roles

    for (int sub = 0; sub < 2; ++sub) {
        int jloc = (jcc*2 + sub) * 64;
        size_t jbase = (size_t)b*4096 + jloc;
        // ---- issue stage loads (regs) -- overlaps prev sub's Z phase ----
        s16x8 sv[8];
#pragma unroll
        for (int it = 0; it < 8; ++it) {
            int j = it*8 + jrow;
            sv[it] = *(const s16x8*)(xb + (jbase + j)*256 + cseg*8);
        }
        // ---- dots B-frags direct from global ----
        size_t rowg = jbase + jb16 + l15;
        const u16* xbp = xb + rowg*256 + quad*8;
        s16x8 xv[8];
#pragma unroll
        for (int kc = 0; kc < 8; ++kc) xv[kc] = *(const s16x8*)(xbp + kc*32);
        __syncthreads();   // B1: prev sub's T_s/a_s readers done (q_s ready on sub 0)
#pragma unroll
        for (int it = 0; it < 8; ++it) {
            int j = it*8 + jrow;
            *(s16x8*)(T_s + ts_addr(cseg, j)) = sv[it];
        }
        // ---- dots (overlaps the ds_writes above) ----
        f32x4v accd = (f32x4v){0.f,0.f,0.f,0.f};
#pragma unroll
        for (int kc = 0; kc < 8; ++kc) {
            s16x8 af;
            if (l15 < 8) af = *(const s16x8*)(q_s + l15*264 + kc*32 + quad*8);
            else         af = (s16x8){0,0,0,0,0,0,0,0};
            accd = __builtin_amdgcn_mfma_f32_16x16x32_bf16(af, xv[kc], accd, 0, 0, 0);
        }
        // ---- affine fixup + softmax over i (pairs lane<->lane^16) ----
        float rsj = rs[rowg], mrj = mu[rowg] * rsj;
        float dv[4];
#pragma unroll
        for (int r = 0; r < 4; r++)
            dv[r] = SCALE*(rsj*accd[r] + mrj*kl_s[16 + quad*4 + r] + kl_s[quad*4 + r]);
        float mx = fmaxf(fmaxf(dv[0], dv[1]), fmaxf(dv[2], dv[3]));
        mx = fmaxf(mx, __shfl_xor(mx, 16));
        float ev[4];
        float sum = 0.f;
#pragma unroll
        for (int r = 0; r < 4; r++) { ev[r] = expf(dv[r] - mx); sum += ev[r]; }
        sum += __shfl_xor(sum, 16);
        float inv = 1.f / sum;
#pragma unroll
        for (int r = 0; r < 4; r++) {
            float a = ev[r]*inv + EPS;
            rtot[r] += a;
            ttot[r] += a * mrj;
            a_s[(quad*4 + r)*72 + jb16 + l15] = f2bf(a * rsj);
        }
        __syncthreads();   // B2: T_s + a_s ready
        // ---- Z += a2 . x (conflict-free swizzled gather) ----
#pragma unroll
        for (int ct = 0; ct < 4; ++ct) {
            int c = wave*64 + ct*16 + l15;
            int cb = c >> 3, e = c & 7;
#pragma unroll
            for (int kc2 = 0; kc2 < 2; ++kc2) {
                s16x8 af2 = *(const s16x8*)(a_s + l15*72 + kc2*32 + quad*8);
                s16x8 bv;
#pragma unroll
                for (int t = 0; t < 8; t++) {
                    int jj = kc2*32 + quad*8 + t;
                    bv[t] = (short)T_s[ts_addr(cb, jj) + e];
                }
                accz[ct] = __builtin_amdgcn_mfma_f32_16x16x32_bf16(af2, bv, accz[ct], 0, 0, 0);
            }
        }
    }
    // ---- write partials ----
    if (quad < 2) {
#pragma unroll
        for (int ct = 0; ct < 4; ++ct) {
            int c = wave*64 + ct*16 + l15;
#pragma unroll
            for (int r = 0; r < 4; r++)
                Zp[((size_t)(b*32 + jcc)*8 + quad*4 + r)*256 + c] = accz[ct][r];
        }
    }
#pragma unroll
    for (int r = 0; r < 4; r++) {
        rtot[r] += __shfl_xor(rtot[r], 1);
        rtot[r] += __shfl_xor(rtot[r], 2);
        rtot[r] += __shfl_xor(rtot[r], 4);
        rtot[r] += __shfl_xor(rtot[r], 8);
        ttot[r] += __shfl_xor(ttot[r], 1);
        ttot[r] += __shfl_xor(ttot[r], 2);
        ttot[r] += __shfl_xor(ttot[r], 4);
        ttot[r] += __shfl_xor(ttot[r], 8);
    }
    if (l15 == 0 && quad < 2) {
        int base = ((b*32 + jcc)*4 + wave)*8 + quad*4;
#pragma unroll
        for (int r = 0; r < 4; r++) { Rp[base + r] = rtot[r]; Tp[base + r] = ttot[r]; }
    }
}

// ---------------- reduce Z/R/T -> Ys into A_cat cols 0..255 ----------------
__global__ __launch_bounds__(256) void k_reduce(const float* __restrict__ Zp,
    const float* __restrict__ Rp, const float* __restrict__ Tp,
    const float* __restrict__ liw, const float* __restrict__ lib,
    u16* __restrict__ Acat) {
    int m = blockIdx.x;   // b*8 + i
    int b = m >> 3, i = m & 7, d = threadIdx.x;
    float z = 0.f;
#pragma unroll
    for (int c = 0; c < 32; c++) z += Zp[((size_t)(b*32 + c)*8 + i)*256 + d];
    float rv = 0.f, tv = 0.f;
    if (d < 128) {
        rv = Rp[(size_t)(b*128 + d)*8 + i];
        tv = Tp[(size_t)(b*128 + d)*8 + i];
    }
    __shared__ float redR[4], redT[4];
    rv = warp_sum64(rv); tv = warp_sum64(tv);
    int wave = d >> 6, lane = d & 63;
    if (lane == 0) { redR[wave] = rv; redT[wave] = tv; }
    __syncthreads();
    float R = redR[0]+redR[1]+redR[2]+redR[3];
    float T = redT[0]+redT[1]+redT[2]+redT[3];
    float ys = (liw[d]*(z - T) + lib[d]*R) / R;
    Acat[(size_t)m*512 + d] = f2bf(ys);
}

// ---------------- GRU gates + h + LN_ff(h) ----------------
__global__ __launch_bounds__(256) void k_gates(const float* __restrict__ g,
    const float* __restrict__ slots, const float* __restrict__ lfw,
    const float* __restrict__ lfb, float* __restrict__ h, u16* __restrict__ hln_b) {
    int m = blockIdx.x, d = threadIdx.x;
    const float* gm = g + (size_t)m*1024;
    float r = sigf(gm[d]);
    float z = sigf(gm[256 + d]);
    float nn = tanhf(gm[512 + d] + r * gm[768 + d]);
    float hv = (1.f - z)*nn + z*slots[(size_t)m*256 + d];
    h[(size_t)m*256 + d] = hv;
    __shared__ float red[8];
    float su = warp_sum64(hv), sq = warp_sum64(hv*hv);
    int wave = threadIdx.x >> 6, lane = threadIdx.x & 63;
    if (lane == 0) { red[wave] = su; red[4+wave] = sq; }
    __syncthreads();
    float S1 = red[0]+red[1]+red[2]+red[3], S2 = red[4]+red[5]+red[6]+red[7];
    float muv = S1*(1.f/256.f);
    float rsv = rsqrtf(S2*(1.f/256.f) - muv*muv + LN_EPS);
    hln_b[(size_t)m*256 + d] = f2bf((hv - muv)*rsv*lfw[d] + lfb[d]);
}

// ---------------- residual + next LN(slots) + kap/lam ----------------
__global__ __launch_bounds__(256) void k_residual(const float* __restrict__ h,
    const float* __restrict__ ff2, const float* __restrict__ lsw,
    const float* __restrict__ lsb, const float* __restrict__ u1,
    const float* __restrict__ u2, const float* __restrict__ c12,
    float* __restrict__ slots, u16* __restrict__ Acat, u16* __restrict__ s_b,
    float* __restrict__ kap, float* __restrict__ lam) {
    int m = blockIdx.x, d = threadIdx.x;
    float sv = h[(size_t)m*256 + d] + ff2[(size_t)m*256 + d];
    slots[(size_t)m*256 + d] = sv;
    Acat[(size_t)m*512 + 256 + d] = f2bf(sv);
    __shared__ float red[16];
    float su = warp_sum64(sv), sq = warp_sum64(sv*sv);
    int wave = threadIdx.x >> 6, lane = threadIdx.x & 63;
    if (lane == 0) { red[wave] = su; red[4+wave] = sq; }
    __syncthreads();
    float S1 = red[0]+red[1]+red[2]+red[3], S2 = red[4]+red[5]+red[6]+red[7];
    float muv = S1*(1.f/256.f);
    float rsv = rsqrtf(S2*(1.f/256.f) - muv*muv + LN_EPS);
    float sn = (sv - muv)*rsv*lsw[d] + lsb[d];
    s_b[(size_t)m*256 + d] = f2bf(sn);
    float ks = warp_sum64(sn * u1[d]), ls = warp_sum64(sn * u2[d]);
    if (lane == 0) { red[8+wave] = ks; red[12+wave] = ls; }
    __syncthreads();
    if (threadIdx.x == 0) {
        kap[m] = red[8]+red[9]+red[10]+red[11] + c12[0];
        lam[m] = red[12]+red[13]+red[14]+red[15] + c12[1];
    }
}

// ---------------- final output ----------------
__global__ __launch_bounds__(256) void k_out(const float* __restrict__ slots,
                                             void* __restrict__ out, const int* flagp) {
    int bf = *flagp;
    int i = blockIdx.x * 256 + threadIdx.x;
    if (bf) ((u16*)out)[i] = f2bf(slots[i]);
    else    ((float*)out)[i] = slots[i];
}

extern "C" void kernel_launch(void* const* d_in, const int* in_sizes, int n_in,
                              void* d_out, int out_size, void* d_ws, size_t ws_size,
                              hipStream_t stream) {
    (void)in_sizes; (void)n_in; (void)out_size; (void)ws_size;
    const void* inputs    = d_in[0];
    const void* query_pos = d_in[1];
    const void* wq   = d_in[2];  const void* bq   = d_in[3];
    const void* wk   = d_in[4];  const void* bk   = d_in[5];
    const void* wv   = d_in[6];  const void* bv   = d_in[7];
    const void* w_ih = d_in[8];  const void* b_ih = d_in[9];
    const void* w_hh = d_in[10]; const void* b_hh = d_in[11];
    const void* w1   = d_in[12]; const void* b1   = d_in[13];
    const void* w2   = d_in[14]; const void* b2   = d_in[15];
    const void* ln_in_w = d_in[16]; const void* ln_in_b = d_in[17];
    const void* ln_s_w  = d_in[18]; const void* ln_s_b  = d_in[19];
    const void* ln_ff_w = d_in[20]; const void* ln_ff_b = d_in[21];

    char* w = (char*)d_ws;
    size_t off = 0;
    auto alloc = [&](size_t bytes) -> void* {
        void* p = w + off;
        off = (off + bytes + 255) & ~(size_t)255;
        return p;
    };
    u16*   XB     = (u16*)alloc(134217728);    // bf16 copy of x (f32-input path only)
    float* Zp     = (float*)alloc(16777216);   // [64*32][8][256] f32
    float* gates  = (float*)alloc(2097152);    // [512][1024] f32
    u16*   Wbig_b = (u16*)alloc(1048576);      // [1024][512]
    u16*   Wc2_b  = (u16*)alloc(393216);       // [768][256]
    u16*   Wc_b   = (u16*)alloc(131072);       // [256][256]
    u16*   wqT_b  = (u16*)alloc(131072);
    u16*   wvT_b  = (u16*)alloc(131072);
    u16*   wk2_b  = (u16*)alloc(131072);
    u16*   wih_b  = (u16*)alloc(393216);
    u16*   whh_b  = (u16*)alloc(393216);
    u16*   w1_b   = (u16*)alloc(262144);
    u16*   w2_b   = (u16*)alloc(262144);
    float* mu     = (float*)alloc(1048576);
    float* rs     = (float*)alloc(1048576);
    float* slots  = (float*)alloc(524288);
    u16*   s_b    = (u16*)alloc(262144);
    u16*   Acat   = (u16*)alloc(524288);       // [512][512]: [Ys | slots]
    u16*   q2_b   = (u16*)alloc(262144);
    float* h      = (float*)alloc(524288);
    u16*   hln_b  = (u16*)alloc(262144);
    u16*   ff1_b  = (u16*)alloc(524288);
    float* ff2    = (float*)alloc(524288);
    float* Rp     = (float*)alloc(262144);
    float* Tp     = (float*)alloc(262144);
    float* bq_f   = (float*)alloc(1024);
    float* bk_f   = (float*)alloc(1024);
    float* bv_f   = (float*)alloc(1024);
    float* bih_f  = (float*)alloc(3072);
    float* bhh_f  = (float*)alloc(3072);
    float* b1_f   = (float*)alloc(2048);
    float* b2_f   = (float*)alloc(1024);
    float* liw_f  = (float*)alloc(1024);
    float* lib_f  = (float*)alloc(1024);
    float* lsw_f  = (float*)alloc(1024);
    float* lsb_f  = (float*)alloc(1024);
    float* lfw_f  = (float*)alloc(1024);
    float* lfb_f  = (float*)alloc(1024);
    float* m1p    = (float*)alloc(1024);
    float* m2p    = (float*)alloc(1024);
    float* u1     = (float*)alloc(1024);
    float* u2     = (float*)alloc(1024);
    float* bq2    = (float*)alloc(1024);
    float* wibv   = (float*)alloc(3072);
    float* bbig   = (float*)alloc(4096);
    float* c12    = (float*)alloc(256);
    float* kap    = (float*)alloc(2048);
    float* lam    = (float*)alloc(2048);
    int*   flag   = (int*)alloc(256);

    // ---- prep ----
    k_sniff<<<1, 64, 0, stream>>>(inputs, flag);
    k_prep_misc<<<18, 256, 0, stream>>>(bq, bk, bv, b_ih, b_hh, b1, b2,
                                        ln_in_w, ln_in_b, ln_s_w, ln_s_b, ln_ff_w, ln_ff_b,
                                        bq_f, bk_f, bv_f, bih_f, bhh_f, b1_f, b2_f,
                                        liw_f, lib_f, lsw_f, lsb_f, lfw_f, lfb_f, flag);
    k_stats<<<65536, 256, 0, stream>>>(inputs, XB, mu, rs, flag);
    k_prep_w<<<3328, 256, 0, stream>>>(wq, wv, wk, w_ih, w_hh, w1, w2,
                                       wqT_b, wvT_b, wk2_b, wih_b, whh_b, w1_b, w2_b,
                                       liw_f, flag);
    k_prep_m<<<64, 256, 0, stream>>>(wk, liw_f, lib_f, bk_f, m1p, m2p, flag);
    k_prep_u<<<385, 256, 0, stream>>>(wq, wk, w_ih, m1p, m2p, bq_f, bv_f, liw_f,
                                      u1, u2, bq2, wibv, c12, flag);
    k_prep_s<<<512, 256, 0, stream>>>(query_pos, lsw_f, lsb_f, u1, u2, c12,
                                      slots, Acat, s_b, kap, lam, flag);
    gemm64<true, false><<<dim3(4, 4), 256, 0, stream>>>(wk2_b, wqT_b, nullptr, Wc_b, 256, 256);
    gemm64<true, false><<<dim3(12, 4), 256, 0, stream>>>(wih_b, wvT_b, nullptr, Wc2_b, 256, 256);
    k_big<<<2048, 256, 0, stream>>>(Wc2_b, whh_b, bih_f, bhh_f, wibv, Wbig_b, bbig);

    // ---- iterations ----
    for (int step = 0; step < 4; ++step) {
        gemm64<true, false><<<dim3(8, 4), 256, 0, stream>>>(s_b, Wc_b, bq2, q2_b, 256, 256);
        k_attn<<<dim3(32, 64), 256, 0, stream>>>(inputs, XB, q2_b, kap, lam, mu, rs, flag, Zp, Rp, Tp);
        k_reduce<<<512, 256, 0, stream>>>(Zp, Rp, Tp, liw_f, lib_f, Acat);
        gemm64<false, false><<<dim3(8, 16), 256, 0, stream>>>(Acat, Wbig_b, bbig, gates, 1024, 512);
        k_gates<<<512, 256, 0, stream>>>(gates, slots, lfw_f, lfb_f, h, hln_b);
        gemm64<true, true ><<<dim3(8, 8), 256, 0, stream>>>(hln_b, w1_b, b1_f, ff1_b, 512, 256);
        gemm64<false, false><<<dim3(8, 4), 256, 0, stream>>>(ff1_b, w2_b, b2_f, ff2, 256, 512);
        k_residual<<<512, 256, 0, stream>>>(h, ff2, lsw_f, lsb_f, u1, u2, c12,
                                            slots, Acat, s_b, kap, lam);
    }
    k_out<<<512, 256, 0, stream>>>(slots, d_out, flag);
}